// Round 1
// baseline (605.406 us; speedup 1.0000x reference)
//
#include <hip/hip_runtime.h>

#define E_N 200000
#define T_N 500000

typedef __attribute__((ext_vector_type(8))) short bf16x8;
typedef __attribute__((ext_vector_type(4))) float f32x4;
typedef unsigned short u16;
typedef unsigned int u32;

// XOR swizzle for [row][128] bf16 LDS tiles (256B rows): spreads the 32-way
// column-read bank conflict across 8 16B slots. Involution; preserves 16B align.
#define SWZ(b) ((b) ^ ((((b) >> 8) & 7) << 4))

__device__ __forceinline__ u16 f2bf(float f){
  u32 u = __float_as_uint(f);
  return (u16)((u + 0x7fffu + ((u >> 16) & 1u)) >> 16);
}
__device__ __forceinline__ float silu_f(float v){
  return __fdividef(v, 1.f + __expf(-v));
}
__device__ __forceinline__ void gl_lds16(const void* g, void* l){
  __builtin_amdgcn_global_load_lds((const __attribute__((address_space(1))) u32*)g,
                                   (__attribute__((address_space(3))) u32*)l, 16, 0, 0);
}

// One wave computes 16 rows x 128 cols: A rows wv*16.., B = BT[n][k] swizzled.
__device__ __forceinline__ void gemm_tile(const char* ldsA, const char* ldsB,
                                          int wv, int lane, f32x4 acc[8]){
  const int arow = wv*16 + (lane & 15);
  const int kof = (lane >> 4) << 3;
  #pragma unroll
  for (int kc = 0; kc < 4; kc++){
    const int kb = (kc*32 + kof)*2;
    bf16x8 a = *(const bf16x8*)(ldsA + SWZ(arow*256 + kb));
    #pragma unroll
    for (int n = 0; n < 8; n++){
      bf16x8 b = *(const bf16x8*)(ldsB + SWZ((n*16 + (lane & 15))*256 + kb));
      acc[n] = __builtin_amdgcn_mfma_f32_16x16x32_bf16(a, b, acc[n], 0, 0, 0);
    }
  }
}

// ---- prep: W [128][8*128] f32 -> bf16 (native layout already BT[n][k]) ----
__global__ __launch_bounds__(256) void k_cvt_W(const float* __restrict__ W, u16* __restrict__ out){
  int i = blockIdx.x*256 + threadIdx.x;   // 131072 total
  out[i] = f2bf(W[i]);
}

// ---- prep: 9 linear weights [k][n] f32 -> transposed bf16 [n][k] ----
__global__ __launch_bounds__(256) void k_cvt_T(const float* __restrict__ jiw, const float* __restrict__ kjw,
                                               const float* __restrict__ bw, const float* __restrict__ lw,
                                               const float* __restrict__ aw, u16* __restrict__ out){
  int i = blockIdx.x*256 + threadIdx.x;   // 9*16384 total
  int m = i >> 14, o = i & 16383;
  int n = o >> 7, k = o & 127;
  const float* src;
  switch (m){
    case 0: src = jiw; break;
    case 1: src = kjw; break;
    case 2: src = bw; break;
    case 3: src = bw + 16384; break;
    case 4: src = lw; break;
    default: src = aw + (m - 5)*16384; break;
  }
  out[i] = f2bf(src[k*128 + n]);
}

// ---- edge kernel: x_ji = silu(x@Wji+b) -> d_out; x_kj = silu(x@Wkj+b)*rbf_p -> bf16 ws ----
__global__ __launch_bounds__(256) void k_edge(const float* __restrict__ x, const float* __restrict__ rbf,
    const float* __restrict__ rbfw, const u16* __restrict__ wji, const u16* __restrict__ wkj,
    const float* __restrict__ bji, const float* __restrict__ bkj,
    float* __restrict__ out, u16* __restrict__ xkj)
{
  __shared__ __align__(16) char ldsA[16384];
  __shared__ __align__(16) char ldsB[32768];
  __shared__ float lrbf[64*6];
  __shared__ float lrbfw[6*128];
  __shared__ float lbj[128];
  __shared__ float lbk[128];
  const int tid = threadIdx.x;
  const int e0 = blockIdx.x * 64;

  // stage A: 64x128 f32 -> bf16, swizzled
  #pragma unroll
  for (int it = 0; it < 4; it++){
    int i = it*256 + tid;
    int row = i >> 4, c8 = (i & 15) << 3;
    const float4* s = (const float4*)(x + (e0 + row)*128 + c8);
    float4 v0 = s[0], v1 = s[1];
    union { u16 us[8]; uint4 q; } u;
    u.us[0]=f2bf(v0.x); u.us[1]=f2bf(v0.y); u.us[2]=f2bf(v0.z); u.us[3]=f2bf(v0.w);
    u.us[4]=f2bf(v1.x); u.us[5]=f2bf(v1.y); u.us[6]=f2bf(v1.z); u.us[7]=f2bf(v1.w);
    *(uint4*)(ldsA + SWZ(row*256 + c8*2)) = u.q;
  }
  // stage B = Wji (pre-swizzled source, linear LDS dest)
  #pragma unroll
  for (int it = 0; it < 8; it++){
    int p = (it*256 + tid)*16;
    int pb = __builtin_amdgcn_readfirstlane(p);
    int n = p >> 8, o = p & 255;
    gl_lds16((const char*)wji + n*256 + (o ^ ((n & 7) << 4)), ldsB + pb);
  }
  for (int i = tid; i < 384; i += 256) lrbf[i] = rbf[e0*6 + i];
  for (int i = tid; i < 768; i += 256) lrbfw[i] = rbfw[i];
  if (tid < 128){ lbj[tid] = bji[tid]; lbk[tid] = bkj[tid]; }
  __syncthreads();

  const int wv = tid >> 6, lane = tid & 63;
  const int colb = lane & 15, rgrp = (lane >> 4) << 2;
  f32x4 acc[8];
  #pragma unroll
  for (int n = 0; n < 8; n++)
    #pragma unroll
    for (int r = 0; r < 4; r++) acc[n][r] = 0.f;
  gemm_tile(ldsA, ldsB, wv, lane, acc);
  #pragma unroll
  for (int n = 0; n < 8; n++){
    int col = n*16 + colb;
    float b = lbj[col];
    #pragma unroll
    for (int r = 0; r < 4; r++){
      int row = e0 + wv*16 + rgrp + r;
      out[row*128 + col] = silu_f(acc[n][r] + b);
    }
  }
  __syncthreads();   // all ldsB reads done
  #pragma unroll
  for (int it = 0; it < 8; it++){
    int p = (it*256 + tid)*16;
    int pb = __builtin_amdgcn_readfirstlane(p);
    int n = p >> 8, o = p & 255;
    gl_lds16((const char*)wkj + n*256 + (o ^ ((n & 7) << 4)), ldsB + pb);
  }
  __syncthreads();
  #pragma unroll
  for (int n = 0; n < 8; n++)
    #pragma unroll
    for (int r = 0; r < 4; r++) acc[n][r] = 0.f;
  gemm_tile(ldsA, ldsB, wv, lane, acc);

  float rb[4][6];
  #pragma unroll
  for (int r = 0; r < 4; r++)
    #pragma unroll
    for (int c = 0; c < 6; c++) rb[r][c] = lrbf[(wv*16 + rgrp + r)*6 + c];
  #pragma unroll
  for (int n = 0; n < 8; n++){
    int col = n*16 + colb;
    float b = lbk[col];
    float wc[6];
    #pragma unroll
    for (int c = 0; c < 6; c++) wc[c] = lrbfw[c*128 + col];
    #pragma unroll
    for (int r = 0; r < 4; r++){
      float rp = 0.f;
      #pragma unroll
      for (int c = 0; c < 6; c++) rp += rb[r][c]*wc[c];
      int row = e0 + wv*16 + rgrp + r;
      xkj[row*128 + col] = f2bf(silu_f(acc[n][r] + b) * rp);
    }
  }
}

// ---- triplet kernel: m = (sbf_p outer g) @ W, atomic scatter-add into d_out ----
__global__ __launch_bounds__(512) void k_trip(
    const u16* __restrict__ xkj, const float* __restrict__ sbf, const float* __restrict__ sbfw,
    const int* __restrict__ idx_kj, const int* __restrict__ idx_ji, const u16* __restrict__ Wbf,
    float* __restrict__ out)
{
  __shared__ __align__(16) char ldsG[32768];
  __shared__ __align__(16) char ldsB[32768];
  __shared__ float lss[128*8];
  __shared__ int lji[128];
  __shared__ int lkj[128];
  const int tid = threadIdx.x;
  const int t0 = blockIdx.x * 128;

  { // stage raw sbf rows into ldsB scratch (coalesced)
    float* lsbf = (float*)ldsB;
    for (int i = tid; i < 128*42; i += 512){
      int gi = t0*42 + i;
      lsbf[i] = (gi < T_N*42) ? sbf[gi] : 0.f;
    }
  }
  if (tid < 128){
    int w = t0 + tid;
    lji[tid] = (w < T_N) ? idx_ji[w] : -1;
    lkj[tid] = (w < T_N) ? idx_kj[w] : 0;
  }
  __syncthreads();
  // gather G = x_kj[idx_kj] (async, pre-swizzled source) while computing sbf_p
  #pragma unroll
  for (int it = 0; it < 4; it++){
    int p = (it*512 + tid)*16;
    int pb = __builtin_amdgcn_readfirstlane(p);
    int w = p >> 8, o = p & 255;
    gl_lds16((const char*)xkj + lkj[w]*256 + (o ^ ((w & 7) << 4)), ldsG + pb);
  }
  {
    const float* lsbf = (const float*)ldsB;
    if (tid < 128){
      float a[8];
      #pragma unroll
      for (int k = 0; k < 8; k++) a[k] = 0.f;
      for (int c = 0; c < 42; c++){
        float v = lsbf[tid*42 + c];
        #pragma unroll
        for (int k = 0; k < 8; k++) a[k] += v * sbfw[c*8 + k];
      }
      #pragma unroll
      for (int k = 0; k < 8; k++) lss[tid*8 + k] = a[k];
    }
  }
  __syncthreads();   // sbf reads done, G landed
  // stage W slice j=0
  #pragma unroll
  for (int it = 0; it < 4; it++){
    int p = (it*512 + tid)*16;
    int pb = __builtin_amdgcn_readfirstlane(p);
    int n = p >> 8, o = p & 255;
    gl_lds16((const char*)Wbf + n*2048 + (o ^ ((n & 7) << 4)), ldsB + pb);
  }
  __syncthreads();

  const int wv = tid >> 6, lane = tid & 63;
  const int rowl = wv*16 + (lane & 15);
  const int kof = (lane >> 4) << 3;
  f32x4 acc[8];
  #pragma unroll
  for (int n = 0; n < 8; n++)
    #pragma unroll
    for (int r = 0; r < 4; r++) acc[n][r] = 0.f;

  for (int j = 0; j < 8; j++){
    const float s = lss[rowl*8 + j];
    #pragma unroll
    for (int kc = 0; kc < 4; kc++){
      const int kb = (kc*32 + kof)*2;
      union { bf16x8 v; u32 u[4]; } ga, aa;
      ga.v = *(const bf16x8*)(ldsG + SWZ(rowl*256 + kb));
      #pragma unroll
      for (int q = 0; q < 4; q++){
        float lo = __uint_as_float(ga.u[q] << 16) * s;
        float hi = __uint_as_float(ga.u[q] & 0xffff0000u) * s;
        asm("v_cvt_pk_bf16_f32 %0, %1, %2" : "=v"(aa.u[q]) : "v"(lo), "v"(hi));
      }
      #pragma unroll
      for (int n = 0; n < 8; n++){
        bf16x8 b = *(const bf16x8*)(ldsB + SWZ((n*16 + (lane & 15))*256 + kb));
        acc[n] = __builtin_amdgcn_mfma_f32_16x16x32_bf16(aa.v, b, acc[n], 0, 0, 0);
      }
    }
    if (j < 7){
      __syncthreads();
      #pragma unroll
      for (int it = 0; it < 4; it++){
        int p = (it*512 + tid)*16;
        int pb = __builtin_amdgcn_readfirstlane(p);
        int n = p >> 8, o = p & 255;
        gl_lds16((const char*)Wbf + n*2048 + (j + 1)*256 + (o ^ ((n & 7) << 4)), ldsB + pb);
      }
      __syncthreads();
    }
  }
  const int colb = lane & 15, rgrp = (lane >> 4) << 2;
  #pragma unroll
  for (int n = 0; n < 8; n++){
    const int col = n*16 + colb;
    #pragma unroll
    for (int r = 0; r < 4; r++){
      int e = lji[wv*16 + rgrp + r];
      if (e >= 0) unsafeAtomicAdd(out + e*128 + col, acc[n][r]);
    }
  }
}

// ---- epilogue: residual stack, h kept in registers, 7 GEMMs ----
__global__ __launch_bounds__(256) void k_epi(
    const float* __restrict__ x, float* __restrict__ hio, const u16* __restrict__ wm,
    const float* __restrict__ bb2, const float* __restrict__ linb, const float* __restrict__ ab2)
{
  __shared__ __align__(16) char ldsA[16384];
  __shared__ __align__(16) char ldsB[32768];
  __shared__ float lbias[7][128];
  const int tid = threadIdx.x;
  const int e0 = blockIdx.x * 64;
  if (tid < 128){
    lbias[0][tid] = bb2[tid];
    lbias[1][tid] = bb2[128 + tid];
    lbias[2][tid] = linb[tid];
    lbias[3][tid] = ab2[tid];
    lbias[4][tid] = ab2[128 + tid];
    lbias[5][tid] = ab2[256 + tid];
    lbias[6][tid] = ab2[384 + tid];
  }
  const int wv = tid >> 6, lane = tid & 63;
  const int colb = lane & 15, rgrp = (lane >> 4) << 2;
  float h[8][4], t[8][4];
  f32x4 acc[8];
  #pragma unroll
  for (int n = 0; n < 8; n++)
    #pragma unroll
    for (int r = 0; r < 4; r++)
      h[n][r] = hio[(e0 + wv*16 + rgrp + r)*128 + n*16 + colb];

#define STAGE_B(mi) { \
  _Pragma("unroll") \
  for (int it = 0; it < 8; it++){ \
    int p = (it*256 + tid)*16; \
    int pb = __builtin_amdgcn_readfirstlane(p); \
    int nn = p >> 8, o = p & 255; \
    gl_lds16((const char*)wm + (mi)*32768 + nn*256 + (o ^ ((nn & 7) << 4)), ldsB + pb); \
  } }
#define WRITE_A(v) { \
  _Pragma("unroll") \
  for (int n = 0; n < 8; n++){ \
    _Pragma("unroll") \
    for (int r = 0; r < 4; r++){ \
      int rowl = wv*16 + rgrp + r; \
      *(u16*)(ldsA + SWZ(rowl*256 + (n*16 + colb)*2)) = f2bf(v[n][r]); \
    } } }
#define RUN_GEMM() { \
  _Pragma("unroll") \
  for (int n = 0; n < 8; n++){ \
    _Pragma("unroll") \
    for (int r = 0; r < 4; r++) acc[n][r] = 0.f; } \
  gemm_tile(ldsA, ldsB, wv, lane, acc); }

  // before residual: t = silu(h@W0+b0); h += silu(t@W1+b1)
  STAGE_B(0); WRITE_A(h); __syncthreads(); RUN_GEMM();
  #pragma unroll
  for (int n = 0; n < 8; n++){ float b = lbias[0][n*16 + colb];
    #pragma unroll
    for (int r = 0; r < 4; r++) t[n][r] = silu_f(acc[n][r] + b); }
  __syncthreads(); STAGE_B(1); WRITE_A(t); __syncthreads(); RUN_GEMM();
  #pragma unroll
  for (int n = 0; n < 8; n++){ float b = lbias[1][n*16 + colb];
    #pragma unroll
    for (int r = 0; r < 4; r++) h[n][r] += silu_f(acc[n][r] + b); }
  // h = silu(h@lin+b) + x
  __syncthreads(); STAGE_B(2); WRITE_A(h); __syncthreads(); RUN_GEMM();
  #pragma unroll
  for (int n = 0; n < 8; n++){ float b = lbias[2][n*16 + colb];
    #pragma unroll
    for (int r = 0; r < 4; r++)
      h[n][r] = silu_f(acc[n][r] + b) + x[(e0 + wv*16 + rgrp + r)*128 + n*16 + colb]; }
  // after residual 0
  __syncthreads(); STAGE_B(3); WRITE_A(h); __syncthreads(); RUN_GEMM();
  #pragma unroll
  for (int n = 0; n < 8; n++){ float b = lbias[3][n*16 + colb];
    #pragma unroll
    for (int r = 0; r < 4; r++) t[n][r] = silu_f(acc[n][r] + b); }
  __syncthreads(); STAGE_B(4); WRITE_A(t); __syncthreads(); RUN_GEMM();
  #pragma unroll
  for (int n = 0; n < 8; n++){ float b = lbias[4][n*16 + colb];
    #pragma unroll
    for (int r = 0; r < 4; r++) h[n][r] += silu_f(acc[n][r] + b); }
  // after residual 1
  __syncthreads(); STAGE_B(5); WRITE_A(h); __syncthreads(); RUN_GEMM();
  #pragma unroll
  for (int n = 0; n < 8; n++){ float b = lbias[5][n*16 + colb];
    #pragma unroll
    for (int r = 0; r < 4; r++) t[n][r] = silu_f(acc[n][r] + b); }
  __syncthreads(); STAGE_B(6); WRITE_A(t); __syncthreads(); RUN_GEMM();
  #pragma unroll
  for (int n = 0; n < 8; n++){ float b = lbias[6][n*16 + colb];
    #pragma unroll
    for (int r = 0; r < 4; r++) h[n][r] += silu_f(acc[n][r] + b); }

  #pragma unroll
  for (int n = 0; n < 8; n++)
    #pragma unroll
    for (int r = 0; r < 4; r++)
      hio[(e0 + wv*16 + rgrp + r)*128 + n*16 + colb] = h[n][r];
#undef STAGE_B
#undef WRITE_A
#undef RUN_GEMM
}

extern "C" void kernel_launch(void* const* d_in, const int* in_sizes, int n_in,
                              void* d_out, int out_size, void* d_ws, size_t ws_size,
                              hipStream_t stream)
{
  const float* x    = (const float*)d_in[0];
  const float* rbf  = (const float*)d_in[1];
  const float* sbf  = (const float*)d_in[2];
  const int* idx_kj = (const int*)d_in[3];
  const int* idx_ji = (const int*)d_in[4];
  const float* rbfw = (const float*)d_in[5];
  const float* sbfw = (const float*)d_in[6];
  const float* kjw  = (const float*)d_in[7];
  const float* kjb  = (const float*)d_in[8];
  const float* jiw  = (const float*)d_in[9];
  const float* jib  = (const float*)d_in[10];
  const float* W    = (const float*)d_in[11];
  const float* bw   = (const float*)d_in[12];
  const float* bb   = (const float*)d_in[13];
  const float* lw   = (const float*)d_in[14];
  const float* lb   = (const float*)d_in[15];
  const float* aw   = (const float*)d_in[16];
  const float* ab   = (const float*)d_in[17];
  float* out = (float*)d_out;
  char* ws = (char*)d_ws;
  u16* Wbf  = (u16*)(ws);               // 128x1024 bf16 = 256KB (native BT layout)
  u16* linT = (u16*)(ws + 262144);      // 9 x [128][128] bf16 transposed = 288KB
  u16* xkj  = (u16*)(ws + 1048576);     // E x 128 bf16 = 51.2MB

  k_cvt_W<<<dim3(512), dim3(256), 0, stream>>>(W, Wbf);
  k_cvt_T<<<dim3(576), dim3(256), 0, stream>>>(jiw, kjw, bw, lw, aw, linT);
  k_edge<<<dim3(E_N/64), dim3(256), 0, stream>>>(x, rbf, rbfw, linT, linT + 16384, jib, kjb, out, xkj);
  k_trip<<<dim3((T_N + 127)/128), dim3(512), 0, stream>>>(xkj, sbf, sbfw, idx_kj, idx_ji, Wbf, out);
  k_epi<<<dim3(E_N/64), dim3(256), 0, stream>>>(x, out, linT + 2*16384, bb, lb, ab);
}